// Round 9
// baseline (337.803 us; speedup 1.0000x reference)
//
#include <hip/hip_runtime.h>
#include <math.h>

#define DMODEL 768
#define NHEAD 12
#define DKDIM 64
#define BB 2
#define SS 2048
#define MROWS (BB * SS)          // 4096
#define WELEM (DMODEL * DMODEL)  // 589824
#define MWORDS (SS / 64)         // 32 u64 mask words per row
#define NIT (SS / 64)            // 32 K-tiles

typedef unsigned short bf16_t;
typedef __attribute__((ext_vector_type(8))) short s8;   // 8 bf16 = 4 VGPRs (MFMA A/B frag)
typedef __attribute__((ext_vector_type(4))) float f4;   // MFMA C/D frag

#define MFMA(a, b, c) __builtin_amdgcn_mfma_f32_16x16x32_bf16((a), (b), (c), 0, 0, 0)

__device__ __forceinline__ bf16_t f2bf(float f) {   // round-to-nearest-even
    unsigned u = __float_as_uint(f);
    u += 0x7fffu + ((u >> 16) & 1u);
    return (bf16_t)(u >> 16);
}
// HW packed cvt: attention P-pack only (r6: hurts GEMM staging scheduling).
__device__ __forceinline__ unsigned cvtpk2(float a, float b) {
    unsigned r;
    asm("v_cvt_pk_bf16_f32 %0, %1, %2" : "=v"(r) : "v"(a), "v"(b));
    return r;   // lo = bf16(a), hi = bf16(b)
}
__device__ __forceinline__ s8 ldfrag(const bf16_t* p) {
    union { uint4 u; s8 s; } x;
    x.u = *(const uint4*)p;
    return x.s;
}
// async global->LDS, 16B per lane: LDS dest = wave-uniform base + lane*16.
__device__ __forceinline__ void gload16(const bf16_t* g, bf16_t* l) {
    __builtin_amdgcn_global_load_lds(
        (__attribute__((address_space(1))) void*)g,
        (__attribute__((address_space(3))) void*)l,
        16, 0, 0);
}

// ---------------------------------------------------------------------------
// Weight prepass: fp32 -> bf16, 4 matrices of 768x768. grid (576, 4), 256 thr.
// ---------------------------------------------------------------------------
__global__ void cvt_weights(const float* __restrict__ W0, const float* __restrict__ W1,
                            const float* __restrict__ W2, const float* __restrict__ W3,
                            bf16_t* __restrict__ dst)
{
    const float* src = (blockIdx.y == 0) ? W0 : (blockIdx.y == 1) ? W1
                     : (blockIdx.y == 2) ? W2 : W3;
    bf16_t* d = dst + (size_t)blockIdx.y * WELEM;
    const int i = (blockIdx.x * 256 + threadIdx.x) * 4;
    const float4 v = *(const float4*)(src + i);
    ushort4 h;
    h.x = f2bf(v.x); h.y = f2bf(v.y); h.z = f2bf(v.z); h.w = f2bf(v.w);
    *(ushort4*)(d + i) = h;
}

// ---------------------------------------------------------------------------
// Input prepass: fp32 -> bf16 once (QKV GEMM stages via global_load_lds,
// which cannot convert). grid (3072, 3), 256 thr.
// ---------------------------------------------------------------------------
__global__ __launch_bounds__(256) void cvt_inputs(
    const float* __restrict__ A0, const float* __restrict__ A1,
    const float* __restrict__ A2, bf16_t* __restrict__ dst)
{
    const float* src = (blockIdx.y == 0) ? A0 : (blockIdx.y == 1) ? A1 : A2;
    bf16_t* d = dst + (size_t)blockIdx.y * MROWS * DMODEL;
    const int i = (blockIdx.x * 256 + threadIdx.x) * 4;
    const float4 v = *(const float4*)(src + i);
    ushort4 h;
    h.x = f2bf(v.x); h.y = f2bf(v.y); h.z = f2bf(v.z); h.w = f2bf(v.w);
    *(ushort4*)(d + i) = h;
}

// ---------------------------------------------------------------------------
// Mask prepass: int32 [B,S,S] -> bit-packed u64 words (1 MB, L2-resident).
// ---------------------------------------------------------------------------
__global__ __launch_bounds__(256) void mask_to_bits(
    const int* __restrict__ mask, unsigned long long* __restrict__ mbits)
{
    const size_t gid = (size_t)blockIdx.x * 256 + threadIdx.x;
    const int m = mask[gid];
    const unsigned long long bal = __ballot(m != 0);
    if ((threadIdx.x & 63) == 0) mbits[gid >> 6] = bal;
}

// ---------------------------------------------------------------------------
// QKV GEMM, BK=64 + global_load_lds. The BK=32 version paid 24 barrier-drain
// pairs per block (the structural ~20% m97 stall); BK=64 halves that (12) at
// identical total gloads/ds_reads/MFMAs. LDS 32 KB (A 16 + B 16, no dbuf).
// Swizzle (G21, both-sides): LDS[row][blk] holds global[row][blk^(row&7)];
// staged with linear dest + pre-swizzled per-lane source (row&7 == lane>>3,
// so src blk = (lane&7)^(lane>>3) is lane-constant); frag read at global blk
// g = kk*4+quad uses LDS blk g^(l15&7) -> 2-way bank aliasing only (free).
// grid (6, 32, 3), 256 thr = 4 waves in 2x2.
// ---------------------------------------------------------------------------
__global__ __launch_bounds__(256) void gemm_qkv(
    const bf16_t* __restrict__ A0, const bf16_t* __restrict__ A1, const bf16_t* __restrict__ A2,
    const bf16_t* __restrict__ W0, const bf16_t* __restrict__ W1, const bf16_t* __restrict__ W2,
    const float* __restrict__ bias0, const float* __restrict__ bias1, const float* __restrict__ bias2,
    bf16_t* __restrict__ C0, bf16_t* __restrict__ C1, bf16_t* __restrict__ C2,
    float sc0, float sc1, float sc2)
{
    __shared__ bf16_t As[128 * 64];   // 16 KB
    __shared__ bf16_t Bs[128 * 64];

    const int z = blockIdx.z;
    const bf16_t* A    = (z == 0) ? A0 : (z == 1) ? A1 : A2;
    const bf16_t* W    = (z == 0) ? W0 : (z == 1) ? W1 : W2;
    const float*  bias = (z == 0) ? bias0 : (z == 1) ? bias1 : bias2;
    bf16_t*       C    = (z == 0) ? C0 : (z == 1) ? C1 : C2;
    const float   sc   = (z == 0) ? sc0 : (z == 1) ? sc1 : sc2;

    const int tid  = threadIdx.x;
    const int lane = tid & 63;
    const int w    = tid >> 6;
    const int wm   = w & 1;
    const int wn   = w >> 1;
    const int l15  = lane & 15;
    const int quad = lane >> 4;
    const int m0   = blockIdx.y * 128;
    const int n0   = blockIdx.x * 128;

    // staging geometry: issue i covers chunks i*256 + w*64 + lane
    const int lrow = lane >> 3;                 // row-within-8 (== row&7)
    const int lblk = (lane & 7) ^ lrow;         // pre-swizzled source block
    const bf16_t* aS = A + (size_t)(m0 + w * 8 + lrow) * DMODEL + lblk * 8;
    const bf16_t* wS = W + (size_t)(n0 + w * 8 + lrow) * DMODEL + lblk * 8;

    f4 acc[4][4];
    #pragma unroll
    for (int i = 0; i < 4; i++)
        #pragma unroll
        for (int j = 0; j < 4; j++)
            acc[i][j] = (f4){0.f, 0.f, 0.f, 0.f};

    for (int k0 = 0; k0 < DMODEL; k0 += 64) {
        __syncthreads();               // previous step's frag reads done
        #pragma unroll
        for (int i = 0; i < 4; i++) {
            gload16(aS + (size_t)(i * 32) * DMODEL + k0, As + (i * 256 + w * 64) * 8);
            gload16(wS + (size_t)(i * 32) * DMODEL + k0, Bs + (i * 256 + w * 64) * 8);
        }
        __syncthreads();               // vmcnt(0) drained before barrier

        #pragma unroll
        for (int kk = 0; kk < 2; kk++) {
            s8 af[4], bf[4];
            #pragma unroll
            for (int t = 0; t < 4; t++) {
                const int ar  = wm * 64 + t * 16 + l15;
                const int br  = wn * 64 + t * 16 + l15;
                const int blk = (kk * 4 + quad) ^ (l15 & 7);   // ar&7 == l15&7
                af[t] = ldfrag(As + ar * 64 + blk * 8);
                bf[t] = ldfrag(Bs + br * 64 + blk * 8);
            }
            #pragma unroll
            for (int mt = 0; mt < 4; mt++)
                #pragma unroll
                for (int nt = 0; nt < 4; nt++)
                    acc[mt][nt] = MFMA(af[mt], bf[nt], acc[mt][nt]);
        }
    }

    // epilogue: row = m0+64wm+16mt+4quad+reg, col = n0+64wn+16nt+l15
    #pragma unroll
    for (int mt = 0; mt < 4; mt++) {
        #pragma unroll
        for (int nt = 0; nt < 4; nt++) {
            const int col = n0 + wn * 64 + nt * 16 + l15;
            const float bb = bias[col];
            #pragma unroll
            for (int reg = 0; reg < 4; reg++) {
                const int row = m0 + wm * 64 + mt * 16 + quad * 4 + reg;
                C[(size_t)row * DMODEL + col] = f2bf((acc[mt][nt][reg] + bb) * sc);
            }
        }
    }
}

// ---------------------------------------------------------------------------
// Output-projection GEMM, BK=64, reg-staged (192 blocks = 0.75/CU: loads must
// issue BEFORE the first barrier to overlap prior MFMAs; gload can't).
// Same LDS swizzle layout as gemm_qkv; 12 steps instead of 24.
// ---------------------------------------------------------------------------
__global__ __launch_bounds__(256) void gemm_out(
    const bf16_t* __restrict__ A, const bf16_t* __restrict__ W,
    const float* __restrict__ bias, float* __restrict__ C)
{
    __shared__ bf16_t As[128 * 64];
    __shared__ bf16_t Bs[128 * 64];

    const int tid  = threadIdx.x;
    const int lane = tid & 63;
    const int w    = tid >> 6;
    const int wm   = w & 1;
    const int wn   = w >> 1;
    const int l15  = lane & 15;
    const int quad = lane >> 4;
    const int m0   = blockIdx.y * 128;
    const int n0   = blockIdx.x * 128;

    const int srow = tid >> 1;     // 0..127
    const int sh   = tid & 1;      // which 32-k half (4 blocks)
    const int sw7  = srow & 7;

    const bf16_t* aptr = A + (size_t)(m0 + srow) * DMODEL + sh * 32;
    const bf16_t* wptr = W + (size_t)(n0 + srow) * DMODEL + sh * 32;

    f4 acc[4][4];
    #pragma unroll
    for (int i = 0; i < 4; i++)
        #pragma unroll
        for (int j = 0; j < 4; j++)
            acc[i][j] = (f4){0.f, 0.f, 0.f, 0.f};

    for (int k0 = 0; k0 < DMODEL; k0 += 64) {
        uint4 au[4], bu[4];
        #pragma unroll
        for (int j = 0; j < 4; j++) {
            au[j] = *(const uint4*)(aptr + k0 + j * 8);
            bu[j] = *(const uint4*)(wptr + k0 + j * 8);
        }
        __syncthreads();               // previous step's frag reads done
        #pragma unroll
        for (int j = 0; j < 4; j++) {
            const int blk = (sh * 4 + j) ^ sw7;
            *(uint4*)(As + srow * 64 + blk * 8) = au[j];
            *(uint4*)(Bs + srow * 64 + blk * 8) = bu[j];
        }
        __syncthreads();

        #pragma unroll
        for (int kk = 0; kk < 2; kk++) {
            s8 af[4], bf[4];
            #pragma unroll
            for (int t = 0; t < 4; t++) {
                const int ar  = wm * 64 + t * 16 + l15;
                const int br  = wn * 64 + t * 16 + l15;
                const int blk = (kk * 4 + quad) ^ (l15 & 7);
                af[t] = ldfrag(As + ar * 64 + blk * 8);
                bf[t] = ldfrag(Bs + br * 64 + blk * 8);
            }
            #pragma unroll
            for (int mt = 0; mt < 4; mt++)
                #pragma unroll
                for (int nt = 0; nt < 4; nt++)
                    acc[mt][nt] = MFMA(af[mt], bf[nt], acc[mt][nt]);
        }
    }

    #pragma unroll
    for (int mt = 0; mt < 4; mt++) {
        #pragma unroll
        for (int nt = 0; nt < 4; nt++) {
            const int col = n0 + wn * 64 + nt * 16 + l15;
            const float bb = bias[col];
            #pragma unroll
            for (int reg = 0; reg < 4; reg++) {
                const int row = m0 + wm * 64 + mt * 16 + quad * 4 + reg;
                C[(size_t)row * DMODEL + col] = acc[mt][nt][reg] + bb;
            }
        }
    }
}

// ---------------------------------------------------------------------------
// MFMA flash attention — SWAPPED QK^T + bit-mask + shuffle-PV (no Ps LDS).
// grid (S/64, H, B) = 768 blocks (grid-caps occupancy at 3 waves/SIMD, so
// VGPRs are free up to ~170), 256 thr = 4 waves, 16 q-rows each, full K sweep.
//
// Swapped mfma(A=K,B=Q) (same fragment loads) yields S^T: lane holds
// S[k = nt*16+quad*4+reg][q = l15]. Consequences:
//  - mask: lane owns ONE q-row (l15) -> 1 u64 load/iter (r8: 4), bit index
//    is k; extraction ~2 ops/value as before.
//  - l is a single per-lane scalar, reduced once at the end (xor16+xor32).
//  - P -> PV A-frag via 16 __shfl + 8 cndmask per iter (HW-VERIFIED in r7's
//    passing run), replacing r8's Ps round-trip (16 ds_swizzle + 16 masked
//    writes + 4 b128 reads + lgkm waits). r7's regression was its 33.5 MB
//    uncoalesced fbias fetch, now gone. LDS 27.6 -> 18.4 KB.
// Kept from r8: fixed-max exp2 softmax (Q pre-scaled 0.125*log2e), K/mask
// prefetch one iter ahead, V double-buffered in LDS, setprio on MFMA.
// Plain __launch_bounds__ (forcing min-waves spilled 360 MB in r1-2).
// ---------------------------------------------------------------------------
__global__ __launch_bounds__(256) void attn_mfma(
    const bf16_t* __restrict__ Q, const bf16_t* __restrict__ K,
    const bf16_t* __restrict__ V, const unsigned long long* __restrict__ mbits,
    bf16_t* __restrict__ O)
{
    __shared__ unsigned Vs[2][64][36];    // double-buffered V tile [d][kpair]

    const int tid  = threadIdx.x;
    const int lane = tid & 63;
    const int w    = tid >> 6;            // 0..3
    const int l15  = lane & 15;
    const int quad = lane >> 4;
    const int q0   = blockIdx.x * 64;
    const int h    = blockIdx.y;
    const int b    = blockIdx.z;
    const size_t base = ((size_t)b * SS) * DMODEL + (size_t)h * DKDIM;

    // Q as B-operand (col q = l15); K as A-operand (row k = l15): same loads
    const bf16_t* qrow = Q + base + (size_t)(q0 + w * 16 + l15) * DMODEL + quad * 8;
    const s8 qf0 = ldfrag(qrow);
    const s8 qf1 = ldfrag(qrow + 32);

    f4 oacc[4];
    #pragma unroll
    for (int i = 0; i < 4; i++) oacc[i] = (f4){0.f, 0.f, 0.f, 0.f};
    float l_part = 0.0f;                  // denominator partial for q = l15

    const int kp  = tid & 31;
    const int oct = tid >> 5;
    const bf16_t* vbase = V + base + (size_t)(2 * kp) * DMODEL + oct * 8;
    const bf16_t* kbase = K + base + (size_t)l15 * DMODEL + quad * 8;

    // one u64 mask word per iter: row q = l15 of this wave's q-tile
    const unsigned long long* mbase =
        mbits + ((size_t)b * SS + (q0 + w * 16 + l15)) * MWORDS;

    // loop-invariant shuffle sources + select (verified in r7's passing run)
    const int sA  = l15 + (((2 * quad) & 3) << 4);
    const int sB  = l15 + (((2 * quad + 1) & 3) << 4);
    const bool hiQ = (quad & 2) != 0;

    // prologue: stage V tile 0 into Vs[0], prefetch V tile 1 into regs
    uint4 va = *(const uint4*)(vbase);
    uint4 vb = *(const uint4*)(vbase + DMODEL);
    {
        const unsigned short* pa = (const unsigned short*)&va;
        const unsigned short* pb = (const unsigned short*)&vb;
        #pragma unroll
        for (int i = 0; i < 8; i++)
            Vs[0][oct * 8 + i][kp] = (unsigned)pa[i] | ((unsigned)pb[i] << 16);
    }
    va = *(const uint4*)(vbase + (size_t)64 * DMODEL);
    vb = *(const uint4*)(vbase + (size_t)64 * DMODEL + DMODEL);

    // prologue: prefetch K fragments + mask word for iteration 0
    s8 kf0[4], kf1[4];
    unsigned long long mw;
    #pragma unroll
    for (int nt = 0; nt < 4; nt++) {
        const bf16_t* krow = kbase + (size_t)(nt * 16) * DMODEL;
        kf0[nt] = ldfrag(krow);
        kf1[nt] = ldfrag(krow + 32);
    }
    mw = mbase[0];

    __syncthreads();

    for (int it = 0; it < NIT; ++it) {
        const int k0  = it * 64;
        const int cur = it & 1;

        // stage next V tile from prefetched regs; issue prefetch for it+2
        if (it + 1 < NIT) {
            const unsigned short* pa = (const unsigned short*)&va;
            const unsigned short* pb = (const unsigned short*)&vb;
            #pragma unroll
            for (int i = 0; i < 8; i++)
                Vs[cur ^ 1][oct * 8 + i][kp] = (unsigned)pa[i] | ((unsigned)pb[i] << 16);
            if (it + 2 < NIT) {
                va = *(const uint4*)(vbase + (size_t)(k0 + 128) * DMODEL);
                vb = *(const uint4*)(vbase + (size_t)(k0 + 128) * DMODEL + DMODEL);
            }
        }

        // swapped QK^T on prefetched K fragments: sacc = S^T tiles
        f4 sacc[4];
        __builtin_amdgcn_s_setprio(1);
        #pragma unroll
        for (int nt = 0; nt < 4; nt++) {
            f4 zz = {0.f, 0.f, 0.f, 0.f};
            zz = MFMA(kf0[nt], qf0, zz);
            zz = MFMA(kf1[nt], qf1, zz);
            sacc[nt] = zz;
        }
        __builtin_amdgcn_s_setprio(0);

        // prefetch K fragments + mask word for it+1 (hidden under softmax+PV)
        const unsigned long long mwc = mw;
        if (it + 1 < NIT) {
            #pragma unroll
            for (int nt = 0; nt < 4; nt++) {
                const bf16_t* krow = kbase + (size_t)(k0 + 64 + nt * 16) * DMODEL;
                kf0[nt] = ldfrag(krow);
                kf1[nt] = ldfrag(krow + 32);
            }
            mw = mbase[it + 1];
        }

        // fixed-max softmax: p = maskbit ? exp2(s) : 0, pack k-pairs in-lane.
        // bit for value (nt,reg): position nt*16 + quad*4 + reg of mwc.
        const unsigned ml = ((unsigned)mwc) >> (quad * 4);
        const unsigned mh = ((unsigned)(mwc >> 32)) >> (quad * 4);
        unsigned wlo[4], whi[4];
        #pragma unroll
        for (int nt = 0; nt < 4; nt++) {
            const unsigned mm = (nt & 2) ? mh : ml;
            const int shft = (nt & 1) * 16;
            const float p0 = ((mm >> (shft + 0)) & 1u) ? __builtin_exp2f(sacc[nt][0]) : 0.0f;
            const float p1 = ((mm >> (shft + 1)) & 1u) ? __builtin_exp2f(sacc[nt][1]) : 0.0f;
            const float p2 = ((mm >> (shft + 2)) & 1u) ? __builtin_exp2f(sacc[nt][2]) : 0.0f;
            const float p3 = ((mm >> (shft + 3)) & 1u) ? __builtin_exp2f(sacc[nt][3]) : 0.0f;
            l_part += (p0 + p1) + (p2 + p3);
            wlo[nt] = cvtpk2(p0, p1);
            whi[nt] = cvtpk2(p2, p3);
        }

        // P -> PV A-frag among the 4 lanes sharing l15 (r7-verified), then PV
        #pragma unroll
        for (int kt = 0; kt < 2; kt++) {
            const unsigned a0 = (unsigned)__shfl((int)wlo[2 * kt],     sA, 64);
            const unsigned a1 = (unsigned)__shfl((int)wlo[2 * kt + 1], sA, 64);
            const unsigned b0 = (unsigned)__shfl((int)whi[2 * kt],     sA, 64);
            const unsigned b1 = (unsigned)__shfl((int)whi[2 * kt + 1], sA, 64);
            const unsigned c0 = (unsigned)__shfl((int)wlo[2 * kt],     sB, 64);
            const unsigned c1 = (unsigned)__shfl((int)wlo[2 * kt + 1], sB, 64);
            const unsigned d0 = (unsigned)__shfl((int)whi[2 * kt],     sB, 64);
            const unsigned d1 = (unsigned)__shfl((int)whi[2 * kt + 1], sB, 64);
            union { uint4 u; s8 s; } pf;
            pf.u.x = hiQ ? a1 : a0;
            pf.u.y = hiQ ? b1 : b0;
            pf.u.z = hiQ ? c1 : c0;
            pf.u.w = hiQ ? d1 : d0;

            __builtin_amdgcn_s_setprio(1);
            #pragma unroll
            for (int dt = 0; dt < 4; dt++) {
                union { uint4 u; s8 s; } vf;
                vf.u = *(const uint4*)&Vs[cur][dt * 16 + l15][kt * 16 + quad * 4];
                oacc[dt] = MFMA(pf.s, vf.s, oacc[dt]);
            }
            __builtin_amdgcn_s_setprio(0);
        }

        __syncthreads();   // Vs[cur] reads done; Vs[cur^1] writes visible
    }

    // epilogue: reduce l over quads (q = l15), redistribute, normalize, store
    l_part += __shfl_xor(l_part, 16, 64);
    l_part += __shfl_xor(l_part, 32, 64);
    const float inv = 1.0f / l_part;      // valid for q-row l15

    #pragma unroll
    for (int reg = 0; reg < 4; reg++) {
        const float invq = __shfl(inv, (quad << 4) + quad * 4 + reg, 64);
        const size_t row = q0 + w * 16 + quad * 4 + reg;
        #pragma unroll
        for (int dt = 0; dt < 4; dt++) {
            O[base + row * DMODEL + dt * 16 + l15] = f2bf(oacc[dt][reg] * invq);
        }
    }
}

// ---------------------------------------------------------------------------
extern "C" void kernel_launch(void* const* d_in, const int* in_sizes, int n_in,
                              void* d_out, int out_size, void* d_ws, size_t ws_size,
                              hipStream_t stream)
{
    const float* q    = (const float*)d_in[0];
    const float* k    = (const float*)d_in[1];
    const float* v    = (const float*)d_in[2];
    const int*   mask = (const int*)  d_in[3];
    const float* Wq   = (const float*)d_in[4];
    const float* bq   = (const float*)d_in[5];
    const float* Wk   = (const float*)d_in[6];
    const float* bk   = (const float*)d_in[7];
    const float* Wv   = (const float*)d_in[8];
    const float* bv   = (const float*)d_in[9];
    const float* Wo   = (const float*)d_in[10];
    const float* bo   = (const float*)d_in[11];
    float* out = (float*)d_out;

    // workspace (~50 MB): 4 bf16 planes (25.2 MB) + 4 bf16 weights (4.7 MB)
    //                    + 3 bf16 input planes (18.9 MB) + mbits (1 MB)
    bf16_t* wsb = (bf16_t*)d_ws;
    const size_t plane = (size_t)MROWS * DMODEL;   // 3,145,728
    bf16_t* Qp  = wsb;
    bf16_t* Kp  = wsb + plane;
    bf16_t* Vp  = wsb + 2 * plane;
    bf16_t* Ctx = wsb + 3 * plane;
    bf16_t* Wqb = wsb + 4 * plane;
    bf16_t* Wkb = Wqb + WELEM;
    bf16_t* Wvb = Wkb + WELEM;
    bf16_t* Wob = Wvb + WELEM;
    bf16_t* Abf = Wob + WELEM;            // 3 bf16 input planes
    unsigned long long* mbits = (unsigned long long*)(Abf + 3 * plane);

    cvt_weights<<<dim3(WELEM / 1024, 4), 256, 0, stream>>>(Wq, Wk, Wv, Wo, Wqb);
    cvt_inputs<<<dim3((int)(plane / 1024), 3), 256, 0, stream>>>(q, k, v, Abf);
    mask_to_bits<<<dim3((BB * SS * SS) / 256), 256, 0, stream>>>(mask, mbits);

    // fused Q/K/V projections (BK=64, gload_lds staging);
    // Q pre-scaled by 0.125*log2(e) for the exp2 softmax
    gemm_qkv<<<dim3(DMODEL / 128, MROWS / 128, 3), 256, 0, stream>>>(
        Abf, Abf + plane, Abf + 2 * plane, Wqb, Wkb, Wvb, bq, bk, bv,
        Qp, Kp, Vp, 0.125f * 1.44269504f, 1.0f, 1.0f);

    // swapped-QK flash attention: grid (32, 12, 2), 256 thr
    attn_mfma<<<dim3(SS / 64, NHEAD, BB), 256, 0, stream>>>(Qp, Kp, Vp, mbits, Ctx);

    // output projection (BK=64, reg-staged)
    gemm_out<<<dim3(DMODEL / 128, MROWS / 128), 256, 0, stream>>>(Ctx, Wob, bo, out);
}

// Round 11
// 307.604 us; speedup vs baseline: 1.0982x; 1.0982x over previous
//
#include <hip/hip_runtime.h>
#include <math.h>

#define DMODEL 768
#define NHEAD 12
#define DKDIM 64
#define BB 2
#define SS 2048
#define MROWS (BB * SS)          // 4096
#define WELEM (DMODEL * DMODEL)  // 589824
#define MWORDS (SS / 64)         // 32 u64 mask words per row
#define NIT (SS / 64)            // 32 K-tiles

typedef unsigned short bf16_t;
typedef __attribute__((ext_vector_type(8))) short s8;   // 8 bf16 = 4 VGPRs (MFMA A/B frag)
typedef __attribute__((ext_vector_type(4))) float f4;   // MFMA C/D frag

#define MFMA(a, b, c) __builtin_amdgcn_mfma_f32_16x16x32_bf16((a), (b), (c), 0, 0, 0)

__device__ __forceinline__ bf16_t f2bf(float f) {   // round-to-nearest-even
    unsigned u = __float_as_uint(f);
    u += 0x7fffu + ((u >> 16) & 1u);
    return (bf16_t)(u >> 16);
}
// HW packed cvt: attention P-pack only (r6: hurts GEMM staging scheduling).
__device__ __forceinline__ unsigned cvtpk2(float a, float b) {
    unsigned r;
    asm("v_cvt_pk_bf16_f32 %0, %1, %2" : "=v"(r) : "v"(a), "v"(b));
    return r;   // lo = bf16(a), hi = bf16(b)
}
__device__ __forceinline__ s8 ldfrag(const bf16_t* p) {
    union { uint4 u; s8 s; } x;
    x.u = *(const uint4*)p;
    return x.s;
}
// async global->LDS, 16B per lane: LDS dest = wave-uniform base + lane*16.
__device__ __forceinline__ void gload16(const bf16_t* g, bf16_t* l) {
    __builtin_amdgcn_global_load_lds(
        (__attribute__((address_space(1))) void*)g,
        (__attribute__((address_space(3))) void*)l,
        16, 0, 0);
}

// stage 16 consecutive bf16 -> 2 x uint4 (reg-staging path)
__device__ __forceinline__ void ld_stage(const bf16_t* p, uint4& u0, uint4& u1) {
    u0 = *(const uint4*)p;
    u1 = *(const uint4*)(p + 8);
}

// ---------------------------------------------------------------------------
// Weight prepass: fp32 -> bf16, 4 matrices of 768x768. grid (576, 4), 256 thr.
// ---------------------------------------------------------------------------
__global__ void cvt_weights(const float* __restrict__ W0, const float* __restrict__ W1,
                            const float* __restrict__ W2, const float* __restrict__ W3,
                            bf16_t* __restrict__ dst)
{
    const float* src = (blockIdx.y == 0) ? W0 : (blockIdx.y == 1) ? W1
                     : (blockIdx.y == 2) ? W2 : W3;
    bf16_t* d = dst + (size_t)blockIdx.y * WELEM;
    const int i = (blockIdx.x * 256 + threadIdx.x) * 4;
    const float4 v = *(const float4*)(src + i);
    ushort4 h;
    h.x = f2bf(v.x); h.y = f2bf(v.y); h.z = f2bf(v.z); h.w = f2bf(v.w);
    *(ushort4*)(d + i) = h;
}

// ---------------------------------------------------------------------------
// Input prepass: fp32 -> bf16 once (QKV GEMM stages via global_load_lds,
// which cannot convert). grid (3072, 3), 256 thr.
// ---------------------------------------------------------------------------
__global__ __launch_bounds__(256) void cvt_inputs(
    const float* __restrict__ A0, const float* __restrict__ A1,
    const float* __restrict__ A2, bf16_t* __restrict__ dst)
{
    const float* src = (blockIdx.y == 0) ? A0 : (blockIdx.y == 1) ? A1 : A2;
    bf16_t* d = dst + (size_t)blockIdx.y * MROWS * DMODEL;
    const int i = (blockIdx.x * 256 + threadIdx.x) * 4;
    const float4 v = *(const float4*)(src + i);
    ushort4 h;
    h.x = f2bf(v.x); h.y = f2bf(v.y); h.z = f2bf(v.z); h.w = f2bf(v.w);
    *(ushort4*)(d + i) = h;
}

// ---------------------------------------------------------------------------
// Mask prepass: int32 [B,S,S] -> bit-packed u64 words (1 MB, L2-resident).
// ---------------------------------------------------------------------------
__global__ __launch_bounds__(256) void mask_to_bits(
    const int* __restrict__ mask, unsigned long long* __restrict__ mbits)
{
    const size_t gid = (size_t)blockIdx.x * 256 + threadIdx.x;
    const int m = mask[gid];
    const unsigned long long bal = __ballot(m != 0);
    if ((threadIdx.x & 63) == 0) mbits[gid >> 6] = bal;
}

// ---------------------------------------------------------------------------
// QKV GEMM — r8 version (best measured): BK=32 + global_load_lds staging.
// (r9's BK=64 variant regressed ~25 us total; reverted.) 128x128 tile,
// 256 thr = 4 waves in 2x2. G21 both-sides swizzle: linear LDS dest +
// pre-swizzled per-lane source (blk^(row&3)) + swizzled frag read.
// grid (6, 32, 3) = 576 blocks, 2.25/CU.
// ---------------------------------------------------------------------------
__global__ __launch_bounds__(256) void gemm_qkv(
    const bf16_t* __restrict__ A0, const bf16_t* __restrict__ A1, const bf16_t* __restrict__ A2,
    const bf16_t* __restrict__ W0, const bf16_t* __restrict__ W1, const bf16_t* __restrict__ W2,
    const float* __restrict__ bias0, const float* __restrict__ bias1, const float* __restrict__ bias2,
    bf16_t* __restrict__ C0, bf16_t* __restrict__ C1, bf16_t* __restrict__ C2,
    float sc0, float sc1, float sc2)
{
    __shared__ uint4 As4[128 * 4];   // 8 KB, [row][swizzled 16B blk]
    __shared__ uint4 Bs4[128 * 4];

    const int z = blockIdx.z;
    const bf16_t* A    = (z == 0) ? A0 : (z == 1) ? A1 : A2;
    const bf16_t* W    = (z == 0) ? W0 : (z == 1) ? W1 : W2;
    const float*  bias = (z == 0) ? bias0 : (z == 1) ? bias1 : bias2;
    bf16_t*       C    = (z == 0) ? C0 : (z == 1) ? C1 : C2;
    const float   sc   = (z == 0) ? sc0 : (z == 1) ? sc1 : sc2;

    const int tid  = threadIdx.x;
    const int lane = tid & 63;
    const int w    = tid >> 6;
    const int wm   = w & 1;
    const int wn   = w >> 1;
    const int l15  = lane & 15;
    const int quad = lane >> 4;
    const int m0   = blockIdx.y * 128;
    const int n0   = blockIdx.x * 128;

    // per-lane staging sources (pre-swizzled), wave-uniform LDS dests
    const int r0 = tid >> 2,         s0 = (tid & 3) ^ (r0 & 3);
    const int r1 = 64 + (tid >> 2),  s1 = (tid & 3) ^ (r1 & 3);
    const bf16_t* aS0 = A + (size_t)(m0 + r0) * DMODEL + s0 * 8;
    const bf16_t* aS1 = A + (size_t)(m0 + r1) * DMODEL + s1 * 8;
    const bf16_t* wS0 = W + (size_t)(n0 + r0) * DMODEL + s0 * 8;
    const bf16_t* wS1 = W + (size_t)(n0 + r1) * DMODEL + s1 * 8;
    bf16_t* aD0 = (bf16_t*)As4 + w * 512;          // issue 0: chunks 0..255
    bf16_t* aD1 = (bf16_t*)As4 + 2048 + w * 512;   // issue 1: chunks 256..511
    bf16_t* bD0 = (bf16_t*)Bs4 + w * 512;
    bf16_t* bD1 = (bf16_t*)Bs4 + 2048 + w * 512;

    f4 acc[4][4];
    #pragma unroll
    for (int i = 0; i < 4; i++)
        #pragma unroll
        for (int j = 0; j < 4; j++)
            acc[i][j] = (f4){0.f, 0.f, 0.f, 0.f};

    for (int k0 = 0; k0 < DMODEL; k0 += 32) {
        __syncthreads();               // previous iteration's frag reads done
        gload16(aS0 + k0, aD0);
        gload16(aS1 + k0, aD1);
        gload16(wS0 + k0, bD0);
        gload16(wS1 + k0, bD1);
        __syncthreads();               // compiler drains vmcnt(0) before barrier

        s8 af[4], bf[4];
        #pragma unroll
        for (int t = 0; t < 4; t++) {
            const int ar = wm * 64 + t * 16 + l15;
            const int br = wn * 64 + t * 16 + l15;
            union { uint4 u; s8 s; } xa, xb;
            xa.u = As4[ar * 4 + (quad ^ (ar & 3))];
            xb.u = Bs4[br * 4 + (quad ^ (br & 3))];
            af[t] = xa.s;
            bf[t] = xb.s;
        }
        #pragma unroll
        for (int mt = 0; mt < 4; mt++)
            #pragma unroll
            for (int nt = 0; nt < 4; nt++)
                acc[mt][nt] = MFMA(af[mt], bf[nt], acc[mt][nt]);
    }

    // epilogue: row = m0+64wm+16mt+4quad+reg, col = n0+64wn+16nt+l15
    #pragma unroll
    for (int mt = 0; mt < 4; mt++) {
        #pragma unroll
        for (int nt = 0; nt < 4; nt++) {
            const int col = n0 + wn * 64 + nt * 16 + l15;
            const float bb = bias[col];
            #pragma unroll
            for (int reg = 0; reg < 4; reg++) {
                const int row = m0 + wm * 64 + mt * 16 + quad * 4 + reg;
                C[(size_t)row * DMODEL + col] = f2bf((acc[mt][nt][reg] + bb) * sc);
            }
        }
    }
}

// ---------------------------------------------------------------------------
// Output-projection GEMM — 64x128 tile, grid (6, 64) = 384 blocks (1.5/CU).
// The 128x128 version ran 192 blocks = 0.75/CU: 64 CUs idle, the rest at
// 1 wave/SIMD (r9 counters: Occupancy 0.15%, MfmaUtil 0.08 on the slow
// dispatch) — grid-starved. Halving the M-tile doubles block count so every
// CU gets work. Per block: A-tile 64x32 (threads 0-127), B-tile 128x32 (all),
// 4 waves each computing a 64x32 strip (acc 4x2). Reg-staged BK=32 with the
// proven XOR swizzle; 12 KB LDS. Threads >=128 clamp their unused A pointer
// to row m0 (never dereferenced; keeps all formed addresses in-plane).
// ---------------------------------------------------------------------------
__global__ __launch_bounds__(256) void gemm_out(
    const bf16_t* __restrict__ A, const bf16_t* __restrict__ W,
    const float* __restrict__ bias, float* __restrict__ C)
{
    __shared__ uint4 As4[64 * 4];    // 4 KB
    __shared__ uint4 Bs4[128 * 4];   // 8 KB

    const int tid  = threadIdx.x;
    const int lane = tid & 63;
    const int w    = tid >> 6;       // 0..3: 32-col strip
    const int l15  = lane & 15;
    const int quad = lane >> 4;
    const int m0   = blockIdx.y * 64;
    const int n0   = blockIdx.x * 128;

    const int srow  = tid >> 1;      // 0..127 (B rows; A uses 0..63)
    const int shalf = tid & 1;
    const int sw    = srow & 3;
    const int arow  = (tid < 128) ? srow : 0;   // clamp: threads >=128 never use A

    const bf16_t* aptr = A + (size_t)(m0 + arow) * DMODEL + shalf * 16;
    const bf16_t* wptr = W + (size_t)(n0 + srow) * DMODEL + shalf * 16;

    f4 acc[4][2];
    #pragma unroll
    for (int i = 0; i < 4; i++)
        #pragma unroll
        for (int j = 0; j < 2; j++)
            acc[i][j] = (f4){0.f, 0.f, 0.f, 0.f};

    for (int k0 = 0; k0 < DMODEL; k0 += 32) {
        uint4 au0, au1, bu0, bu1;
        if (tid < 128) ld_stage(aptr + k0, au0, au1);
        ld_stage(wptr + k0, bu0, bu1);
        __syncthreads();               // previous step's frag reads done
        if (tid < 128) {
            As4[srow * 4 + ((shalf * 2 + 0) ^ sw)] = au0;
            As4[srow * 4 + ((shalf * 2 + 1) ^ sw)] = au1;
        }
        Bs4[srow * 4 + ((shalf * 2 + 0) ^ sw)] = bu0;
        Bs4[srow * 4 + ((shalf * 2 + 1) ^ sw)] = bu1;
        __syncthreads();

        s8 af[4], bf[2];
        #pragma unroll
        for (int t = 0; t < 4; t++) {
            const int ar = t * 16 + l15;
            union { uint4 u; s8 s; } xa;
            xa.u = As4[ar * 4 + (quad ^ (ar & 3))];
            af[t] = xa.s;
        }
        #pragma unroll
        for (int nt = 0; nt < 2; nt++) {
            const int br = w * 32 + nt * 16 + l15;
            union { uint4 u; s8 s; } xb;
            xb.u = Bs4[br * 4 + (quad ^ (br & 3))];
            bf[nt] = xb.s;
        }
        #pragma unroll
        for (int mt = 0; mt < 4; mt++)
            #pragma unroll
            for (int nt = 0; nt < 2; nt++)
                acc[mt][nt] = MFMA(af[mt], bf[nt], acc[mt][nt]);
    }

    // epilogue: row = m0+16mt+4quad+reg, col = n0+32w+16nt+l15
    #pragma unroll
    for (int mt = 0; mt < 4; mt++) {
        #pragma unroll
        for (int nt = 0; nt < 2; nt++) {
            const int col = n0 + w * 32 + nt * 16 + l15;
            const float bb = bias[col];
            #pragma unroll
            for (int reg = 0; reg < 4; reg++) {
                const int row = m0 + mt * 16 + quad * 4 + reg;
                C[(size_t)row * DMODEL + col] = acc[mt][nt][reg] + bb;
            }
        }
    }
}

// ---------------------------------------------------------------------------
// MFMA flash attention — r9 version (132 us, best measured): SWAPPED QK^T +
// bit-mask + shuffle-PV (no Ps LDS).
// grid (S/64, H, B) = 768 blocks, 256 thr = 4 waves, 16 q-rows/wave.
// Swapped mfma(A=K,B=Q) yields S^T: lane holds S[k=nt*16+quad*4+reg][q=l15].
//  - mask: 1 u64 load/iter (lane owns one q-row).
//  - l: single per-lane scalar, reduced once at the end.
//  - P -> PV A-frag via 16 __shfl + 8 cndmask (r7-verified algebra).
// Fixed-max exp2 softmax (Q pre-scaled 0.125*log2e), K/mask prefetch one
// iter ahead, V double-buffered in LDS, setprio on MFMA clusters.
// ---------------------------------------------------------------------------
__global__ __launch_bounds__(256) void attn_mfma(
    const bf16_t* __restrict__ Q, const bf16_t* __restrict__ K,
    const bf16_t* __restrict__ V, const unsigned long long* __restrict__ mbits,
    bf16_t* __restrict__ O)
{
    __shared__ unsigned Vs[2][64][36];    // double-buffered V tile [d][kpair]

    const int tid  = threadIdx.x;
    const int lane = tid & 63;
    const int w    = tid >> 6;            // 0..3
    const int l15  = lane & 15;
    const int quad = lane >> 4;
    const int q0   = blockIdx.x * 64;
    const int h    = blockIdx.y;
    const int b    = blockIdx.z;
    const size_t base = ((size_t)b * SS) * DMODEL + (size_t)h * DKDIM;

    // Q as B-operand (col q = l15); K as A-operand (row k = l15): same loads
    const bf16_t* qrow = Q + base + (size_t)(q0 + w * 16 + l15) * DMODEL + quad * 8;
    const s8 qf0 = ldfrag(qrow);
    const s8 qf1 = ldfrag(qrow + 32);

    f4 oacc[4];
    #pragma unroll
    for (int i = 0; i < 4; i++) oacc[i] = (f4){0.f, 0.f, 0.f, 0.f};
    float l_part = 0.0f;                  // denominator partial for q = l15

    const int kp  = tid & 31;
    const int oct = tid >> 5;
    const bf16_t* vbase = V + base + (size_t)(2 * kp) * DMODEL + oct * 8;
    const bf16_t* kbase = K + base + (size_t)l15 * DMODEL + quad * 8;

    // one u64 mask word per iter: row q = l15 of this wave's q-tile
    const unsigned long long* mbase =
        mbits + ((size_t)b * SS + (q0 + w * 16 + l15)) * MWORDS;

    // loop-invariant shuffle sources + select (verified in r7's passing run)
    const int sA  = l15 + (((2 * quad) & 3) << 4);
    const int sB  = l15 + (((2 * quad + 1) & 3) << 4);
    const bool hiQ = (quad & 2) != 0;

    // prologue: stage V tile 0 into Vs[0], prefetch V tile 1 into regs
    uint4 va = *(const uint4*)(vbase);
    uint4 vb = *(const uint4*)(vbase + DMODEL);
    {
        const unsigned short* pa = (const unsigned short*)&va;
        const unsigned short* pb = (const unsigned short*)&vb;
        #pragma unroll
        for (int i = 0; i < 8; i++)
            Vs[0][oct * 8 + i][kp] = (unsigned)pa[i] | ((unsigned)pb[i] << 16);
    }
    va = *(const uint4*)(vbase + (size_t)64 * DMODEL);
    vb = *(const uint4*)(vbase + (size_t)64 * DMODEL + DMODEL);

    // prologue: prefetch K fragments + mask word for iteration 0
    s8 kf0[4], kf1[4];
    unsigned long long mw;
    #pragma unroll
    for (int nt = 0; nt < 4; nt++) {
        const bf16_t* krow = kbase + (size_t)(nt * 16) * DMODEL;
        kf0[nt] = ldfrag(krow);
        kf1[nt] = ldfrag(krow + 32);
    }
    mw = mbase[0];

    __syncthreads();

    for (int it = 0; it < NIT; ++it) {
        const int k0  = it * 64;
        const int cur = it & 1;

        // stage next V tile from prefetched regs; issue prefetch for it+2
        if (it + 1 < NIT) {
            const unsigned short* pa = (const unsigned short*)&va;
            const unsigned short* pb = (const unsigned short*)&vb;
            #pragma unroll
            for (int i = 0; i < 8; i++)
                Vs[cur ^ 1][oct * 8 + i][kp] = (unsigned)pa[i] | ((unsigned)pb[i] << 16);
            if (it + 2 < NIT) {
                va = *(const uint4*)(vbase + (size_t)(k0 + 128) * DMODEL);
                vb = *(const uint4*)(vbase + (size_t)(k0 + 128) * DMODEL + DMODEL);
            }
        }

        // swapped QK^T on prefetched K fragments: sacc = S^T tiles
        f4 sacc[4];
        __builtin_amdgcn_s_setprio(1);
        #pragma unroll
        for (int nt = 0; nt < 4; nt++) {
            f4 zz = {0.f, 0.f, 0.f, 0.f};
            zz = MFMA(kf0[nt], qf0, zz);
            zz = MFMA(kf1[nt], qf1, zz);
            sacc[nt] = zz;
        }
        __builtin_amdgcn_s_setprio(0);

        // prefetch K fragments + mask word for it+1 (hidden under softmax+PV)
        const unsigned long long mwc = mw;
        if (it + 1 < NIT) {
            #pragma unroll
            for (int nt = 0; nt < 4; nt++) {
                const bf16_t* krow = kbase + (size_t)(k0 + 64 + nt * 16) * DMODEL;
                kf0[nt] = ldfrag(krow);
                kf1[nt] = ldfrag(krow + 32);
            }
            mw = mbase[it + 1];
        }

        // fixed-max softmax: p = maskbit ? exp2(s) : 0, pack k-pairs in-lane.
        // bit for value (nt,reg): position nt*16 + quad*4 + reg of mwc.
        const unsigned ml = ((unsigned)mwc) >> (quad * 4);
        const unsigned mh = ((unsigned)(mwc >> 32)) >> (quad * 4);
        unsigned wlo[4], whi[4];
        #pragma unroll
        for (int nt = 0; nt < 4; nt++) {
            const unsigned mm = (nt & 2) ? mh : ml;
            const int shft = (nt & 1) * 16;
            const float p0 = ((mm >> (shft + 0)) & 1u) ? __builtin_exp2f(sacc[nt][0]) : 0.0f;
            const float p1 = ((mm >> (shft + 1)) & 1u) ? __builtin_exp2f(sacc[nt][1]) : 0.0f;
            const float p2 = ((mm >> (shft + 2)) & 1u) ? __builtin_exp2f(sacc[nt][2]) : 0.0f;
            const float p3 = ((mm >> (shft + 3)) & 1u) ? __builtin_exp2f(sacc[nt][3]) : 0.0f;
            l_part += (p0 + p1) + (p2 + p3);
            wlo[nt] = cvtpk2(p0, p1);
            whi[nt] = cvtpk2(p2, p3);
        }

        // P -> PV A-frag among the 4 lanes sharing l15 (r7-verified), then PV
        #pragma unroll
        for (int kt = 0; kt < 2; kt++) {
            const unsigned a0 = (unsigned)__shfl((int)wlo[2 * kt],     sA, 64);
            const unsigned a1 = (unsigned)__shfl((int)wlo[2 * kt + 1], sA, 64);
            const unsigned b0 = (unsigned)__shfl((int)whi[2 * kt],     sA, 64);
            const unsigned b1 = (unsigned)__shfl((int)whi[2 * kt + 1], sA, 64);
            const unsigned c0 = (unsigned)__shfl((int)wlo[2 * kt],     sB, 64);
            const unsigned c1 = (unsigned)__shfl((int)wlo[2 * kt + 1], sB, 64);
            const unsigned d0 = (unsigned)__shfl((int)whi[2 * kt],     sB, 64);
            const unsigned d1 = (unsigned)__shfl((int)whi[2 * kt + 1], sB, 64);
            union { uint4 u; s8 s; } pf;
            pf.u.x = hiQ ? a1 : a0;
            pf.u.y = hiQ ? b1 : b0;
            pf.u.z = hiQ ? c1 : c0;
            pf.u.w = hiQ ? d1 : d0;

            __builtin_amdgcn_s_setprio(1);
            #pragma unroll
            for (int dt = 0; dt < 4; dt++) {
                union { uint4 u; s8 s; } vf;
                vf.u = *(const uint4*)&Vs[cur][dt * 16 + l15][kt * 16 + quad * 4];
                oacc[dt] = MFMA(pf.s, vf.s, oacc[dt]);
            }
            __builtin_amdgcn_s_setprio(0);
        }

        __syncthreads();   // Vs[cur] reads done; Vs[cur^1] writes visible
    }

    // epilogue: reduce l over quads (q = l15), redistribute, normalize, store
    l_part += __shfl_xor(l_part, 16, 64);
    l_part += __shfl_xor(l_part, 32, 64);
    const float inv = 1.0f / l_part;      // valid for q-row l15

    #pragma unroll
    for (int reg = 0; reg < 4; reg++) {
        const float invq = __shfl(inv, (quad << 4) + quad * 4 + reg, 64);
        const size_t row = q0 + w * 16 + quad * 4 + reg;
        #pragma unroll
        for (int dt = 0; dt < 4; dt++) {
            O[base + row * DMODEL + dt * 16 + l15] = f2bf(oacc[dt][reg] * invq);
        }
    }
}

// ---------------------------------------------------------------------------
extern "C" void kernel_launch(void* const* d_in, const int* in_sizes, int n_in,
                              void* d_out, int out_size, void* d_ws, size_t ws_size,
                              hipStream_t stream)
{
    const float* q    = (const float*)d_in[0];
    const float* k    = (const float*)d_in[1];
    const float* v    = (const float*)d_in[2];
    const int*   mask = (const int*)  d_in[3];
    const float* Wq   = (const float*)d_in[4];
    const float* bq   = (const float*)d_in[5];
    const float* Wk   = (const float*)d_in[6];
    const float* bk   = (const float*)d_in[7];
    const float* Wv   = (const float*)d_in[8];
    const float* bv   = (const float*)d_in[9];
    const float* Wo   = (const float*)d_in[10];
    const float* bo   = (const float*)d_in[11];
    float* out = (float*)d_out;

    // workspace (~50 MB): 4 bf16 planes (25.2 MB) + 4 bf16 weights (4.7 MB)
    //                    + 3 bf16 input planes (18.9 MB) + mbits (1 MB)
    bf16_t* wsb = (bf16_t*)d_ws;
    const size_t plane = (size_t)MROWS * DMODEL;   // 3,145,728
    bf16_t* Qp  = wsb;
    bf16_t* Kp  = wsb + plane;
    bf16_t* Vp  = wsb + 2 * plane;
    bf16_t* Ctx = wsb + 3 * plane;
    bf16_t* Wqb = wsb + 4 * plane;
    bf16_t* Wkb = Wqb + WELEM;
    bf16_t* Wvb = Wkb + WELEM;
    bf16_t* Wob = Wvb + WELEM;
    bf16_t* Abf = Wob + WELEM;            // 3 bf16 input planes
    unsigned long long* mbits = (unsigned long long*)(Abf + 3 * plane);

    cvt_weights<<<dim3(WELEM / 1024, 4), 256, 0, stream>>>(Wq, Wk, Wv, Wo, Wqb);
    cvt_inputs<<<dim3((int)(plane / 1024), 3), 256, 0, stream>>>(q, k, v, Abf);
    mask_to_bits<<<dim3((BB * SS * SS) / 256), 256, 0, stream>>>(mask, mbits);

    // fused Q/K/V projections (BK=32, gload_lds staging — r8 version);
    // Q pre-scaled by 0.125*log2(e) for the exp2 softmax
    gemm_qkv<<<dim3(DMODEL / 128, MROWS / 128, 3), 256, 0, stream>>>(
        Abf, Abf + plane, Abf + 2 * plane, Wqb, Wkb, Wvb, bq, bk, bv,
        Qp, Kp, Vp, 0.125f * 1.44269504f, 1.0f, 1.0f);

    // swapped-QK flash attention: grid (32, 12, 2), 256 thr
    attn_mfma<<<dim3(SS / 64, NHEAD, BB), 256, 0, stream>>>(Qp, Kp, Vp, mbits, Ctx);

    // output projection: 64x128 tile, grid (6, 64) = 384 blocks (1.5/CU)
    gemm_out<<<dim3(DMODEL / 128, MROWS / 64), 256, 0, stream>>>(Ctx, Wob, bo, out);
}